// Round 1
// baseline (87.376 us; speedup 1.0000x reference)
//
#include <hip/hip_runtime.h>
#include <math.h>

// Attention pooling, B=32, S=4096, ENC=512.
// context[b,e] = sum_s softmax_s(enc[b,s,:]·w_enc) * enc[b,s,e]
// (hidden/w_dec/bias add a per-b constant to the energies -> softmax-invariant -> ignored)

#define B_ 32
#define S_ 4096
#define ENC_ 512
#define TPB 256

__global__ __launch_bounds__(TPB) void attn_partial(
    const float* __restrict__ enc,   // [B, S, 512]
    const float* __restrict__ W,     // [1, 1024]; first 512 = w_enc
    float* __restrict__ pm,          // [B*P] partial max
    float* __restrict__ pl,          // [B*P] partial sum
    float* __restrict__ pc,          // [B*P, 512] partial context
    int R, int P)                    // R = rows per chunk (multiple of 16)
{
    const int b     = blockIdx.y;
    const int chunk = blockIdx.x;
    const int tid   = threadIdx.x;
    const int lane  = tid & 63;
    const int wave  = tid >> 6;
    const int half  = tid >> 7;        // which of the 2 rows per step
    const int colg  = tid & 127;
    const int col   = colg << 2;       // 0..508, 4 cols per thread

    __shared__ float red[2][4][8];     // [buf][wave][step]
    __shared__ float csh[ENC_];        // half-1 partial context for final combine

    const float4 w4 = *reinterpret_cast<const float4*>(W + col);

    float4 c4 = {0.f, 0.f, 0.f, 0.f};
    float m = -INFINITY, l = 0.f;

    const float* base = enc + ((size_t)b * S_ + (size_t)chunk * R) * ENC_ + col;

    int buf = 0;
    for (int rb = 0; rb < R; rb += 16) {
        // 8 steps; step i, this thread handles row rb + 2*i + half
        float4 d[8];
        float part[8];
        const float* p0 = base + (size_t)(rb + half) * ENC_;
#pragma unroll
        for (int i = 0; i < 8; ++i)
            d[i] = *reinterpret_cast<const float4*>(p0 + (size_t)i * (2 * ENC_));
#pragma unroll
        for (int i = 0; i < 8; ++i)
            part[i] = d[i].x * w4.x + d[i].y * w4.y + d[i].z * w4.z + d[i].w * w4.w;

        // full-wave reduction of each step's partial
#pragma unroll
        for (int i = 0; i < 8; ++i) {
            float v = part[i];
#pragma unroll
            for (int ofs = 32; ofs >= 1; ofs >>= 1) v += __shfl_xor(v, ofs, 64);
            part[i] = v;
        }
        if (lane == 0) {
#pragma unroll
            for (int i = 0; i < 8; ++i) red[buf][wave][i] = part[i];
        }
        __syncthreads();

        // row 2i   -> waves 0+1 ; row 2i+1 -> waves 2+3  (broadcast reads)
        float E[16];
#pragma unroll
        for (int i = 0; i < 8; ++i) {
            E[2 * i]     = red[buf][0][i] + red[buf][1][i];
            E[2 * i + 1] = red[buf][2][i] + red[buf][3][i];
        }

        // online softmax update (identical on every thread)
        float mb = E[0];
#pragma unroll
        for (int r = 1; r < 16; ++r) mb = fmaxf(mb, E[r]);
        const float mn = fmaxf(m, mb);
        const float sc = __expf(m - mn);   // first iter: exp(-inf)=0
        c4.x *= sc; c4.y *= sc; c4.z *= sc; c4.w *= sc;
        l *= sc;
        m = mn;

        float p[16];
        float ls = 0.f;
#pragma unroll
        for (int r = 0; r < 16; ++r) { p[r] = __expf(E[r] - mn); ls += p[r]; }
        l += ls;

#pragma unroll
        for (int i = 0; i < 8; ++i) {
            const float w = p[2 * i + half];
            c4.x += w * d[i].x; c4.y += w * d[i].y;
            c4.z += w * d[i].z; c4.w += w * d[i].w;
        }
        buf ^= 1;
        // double-buffered `red`: next write goes to other buffer; safe with one barrier
    }

    // combine the two halves' column accumulators: c[col] = c4(t) + c4(t+128)
    if (half == 1) *reinterpret_cast<float4*>(&csh[col]) = c4;
    __syncthreads();

    const int idx = b * P + chunk;
    if (half == 0) {
        const float4 o = *reinterpret_cast<const float4*>(&csh[col]);
        float4 r;
        r.x = c4.x + o.x; r.y = c4.y + o.y; r.z = c4.z + o.z; r.w = c4.w + o.w;
        *reinterpret_cast<float4*>(pc + (size_t)idx * ENC_ + col) = r;
    }
    if (tid == 0) { pm[idx] = m; pl[idx] = l; }
}

__global__ __launch_bounds__(TPB) void attn_combine(
    const float* __restrict__ pm, const float* __restrict__ pl,
    const float* __restrict__ pc, float* __restrict__ out, int P)
{
    const int b   = blockIdx.x;
    const int tid = threadIdx.x;
    const int col = tid * 2;

    float M = -INFINITY;
    for (int i = 0; i < P; ++i) M = fmaxf(M, pm[b * P + i]);

    float L = 0.f;
    float ax = 0.f, ay = 0.f;
    for (int i = 0; i < P; ++i) {
        const float scv = __expf(pm[b * P + i] - M);
        L += pl[b * P + i] * scv;
        const float2 v = *reinterpret_cast<const float2*>(
            pc + (size_t)(b * P + i) * ENC_ + col);
        ax += v.x * scv; ay += v.y * scv;
    }
    const float inv = 1.f / L;
    out[b * ENC_ + col]     = ax * inv;
    out[b * ENC_ + col + 1] = ay * inv;
}

extern "C" void kernel_launch(void* const* d_in, const int* in_sizes, int n_in,
                              void* d_out, int out_size, void* d_ws, size_t ws_size,
                              hipStream_t stream) {
    const float* enc = (const float*)d_in[0];
    const float* W   = (const float*)d_in[2];
    float* out       = (float*)d_out;

    // pick chunk count P per batch so partials fit in workspace
    int P = 128;
    while (P > 1 && (size_t)B_ * P * (ENC_ + 2) * sizeof(float) > ws_size) P >>= 1;
    const int R = S_ / P;   // >= 32, multiple of 16

    float* pm = (float*)d_ws;
    float* pl = pm + (size_t)B_ * P;
    float* pc = pl + (size_t)B_ * P;

    dim3 grid(P, B_);
    attn_partial<<<grid, TPB, 0, stream>>>(enc, W, pm, pl, pc, R, P);
    attn_combine<<<B_, TPB, 0, stream>>>(pm, pl, pc, out, P);
}

// Round 2
// 72.052 us; speedup vs baseline: 1.2127x; 1.2127x over previous
//
#include <hip/hip_runtime.h>
#include <math.h>

// Attention pooling, B=32, S=4096, ENC=512.
// context[b,e] = sum_s softmax_s(enc[b,s,:]·w_enc) * enc[b,s,e]
// (hidden/w_dec/bias add a per-b constant to energies -> softmax-invariant -> dropped)
//
// Kernel 1: one WAVE per row-chunk. Lane l covers cols [4l,4l+4) and [256+4l,260+4l)
// (two contiguous 1KB wave-loads per row). 64-lane butterfly for the energy dot;
// no LDS, no __syncthreads. Groups of 8 rows, ping-pong register double-buffer so
// the next group's 16 loads are in flight during the current group's reduce/softmax.

#define B_ 32
#define S_ 4096
#define ENC_ 512
#define TPB 256
#define G 8

__device__ __forceinline__ float dot4(const float4 a, const float4 b) {
    return a.x * b.x + a.y * b.y + a.z * b.z + a.w * b.w;
}

__global__ __launch_bounds__(TPB) void attn_partial(
    const float* __restrict__ enc,   // [B, S, 512]
    const float* __restrict__ W,     // [1, 1024]; first 512 = w_enc
    float* __restrict__ pm,          // [B*P] partial max
    float* __restrict__ pl,          // [B*P] partial sum
    float* __restrict__ pc,          // [B*P, 512] partial (unnormalized) context
    int R, int P)                    // R = rows per wave-chunk (multiple of 16)
{
    const int b    = blockIdx.y;
    const int wid  = (blockIdx.x << 2) | (threadIdx.x >> 6);  // chunk id in [0,P)
    const int lane = threadIdx.x & 63;
    const int cA0  = lane << 2;            // cols 4l..4l+3
    const int cB0  = 256 + (lane << 2);    // cols 256+4l..259+4l

    const float4 wA = *reinterpret_cast<const float4*>(W + cA0);
    const float4 wB = *reinterpret_cast<const float4*>(W + cB0);

    const float* row = enc + ((size_t)b * S_ + (size_t)wid * R) * ENC_;

    float4 accA = {0.f, 0.f, 0.f, 0.f}, accB = {0.f, 0.f, 0.f, 0.f};
    float m = -INFINITY, l = 0.f;

    float4 dA0[G], dB0[G], dA1[G], dB1[G];

#define LOADG(DA, DB, base_row) { \
    const float* _p = row + (size_t)(base_row) * ENC_; \
    _Pragma("unroll") \
    for (int i = 0; i < G; ++i) { \
        DA[i] = *reinterpret_cast<const float4*>(_p + (size_t)i * ENC_ + cA0); \
        DB[i] = *reinterpret_cast<const float4*>(_p + (size_t)i * ENC_ + cB0); \
    } }

#define PROC(DA, DB) { \
    float e[G]; \
    _Pragma("unroll") \
    for (int i = 0; i < G; ++i) e[i] = dot4(DA[i], wA) + dot4(DB[i], wB); \
    _Pragma("unroll") \
    for (int i = 0; i < G; ++i) { \
        float v = e[i]; \
        v += __shfl_xor(v, 1, 64);  v += __shfl_xor(v, 2, 64); \
        v += __shfl_xor(v, 4, 64);  v += __shfl_xor(v, 8, 64); \
        v += __shfl_xor(v, 16, 64); v += __shfl_xor(v, 32, 64); \
        e[i] = v; \
    } \
    float gm = e[0]; \
    _Pragma("unroll") \
    for (int i = 1; i < G; ++i) gm = fmaxf(gm, e[i]); \
    const float mn = fmaxf(m, gm); \
    const float sc = __expf(m - mn);  /* first group: exp(-inf)=0 */ \
    m = mn; l *= sc; \
    accA.x *= sc; accA.y *= sc; accA.z *= sc; accA.w *= sc; \
    accB.x *= sc; accB.y *= sc; accB.z *= sc; accB.w *= sc; \
    _Pragma("unroll") \
    for (int i = 0; i < G; ++i) { \
        const float pw = __expf(e[i] - mn); l += pw; \
        accA.x += pw * DA[i].x; accA.y += pw * DA[i].y; \
        accA.z += pw * DA[i].z; accA.w += pw * DA[i].w; \
        accB.x += pw * DB[i].x; accB.y += pw * DB[i].y; \
        accB.z += pw * DB[i].z; accB.w += pw * DB[i].w; \
    } }

    LOADG(dA0, dB0, 0);
    const int ng = R / G;             // even (R multiple of 16)
    for (int g = 0; g < ng; g += 2) {
        if (g + 1 < ng) LOADG(dA1, dB1, (g + 1) * G);
        PROC(dA0, dB0);
        if (g + 2 < ng) LOADG(dA0, dB0, (g + 2) * G);
        if (g + 1 < ng) PROC(dA1, dB1);
    }

    const int idx = b * P + wid;
    *reinterpret_cast<float4*>(pc + (size_t)idx * ENC_ + cA0) = accA;
    *reinterpret_cast<float4*>(pc + (size_t)idx * ENC_ + cB0) = accB;
    if (lane == 0) { pm[idx] = m; pl[idx] = l; }

#undef LOADG
#undef PROC
}

__global__ __launch_bounds__(TPB) void attn_combine(
    const float* __restrict__ pm, const float* __restrict__ pl,
    const float* __restrict__ pc, float* __restrict__ out, int P)
{
    const int b   = blockIdx.y;
    const int col = (blockIdx.x << 8) | threadIdx.x;   // 256 cols per block

    float M = -INFINITY;
    for (int i = 0; i < P; ++i) M = fmaxf(M, pm[b * P + i]);

    float L = 0.f, acc = 0.f;
#pragma unroll 4
    for (int i = 0; i < P; ++i) {
        const float s = __expf(pm[b * P + i] - M);
        L   += pl[b * P + i] * s;
        acc += pc[(size_t)(b * P + i) * ENC_ + col] * s;
    }
    out[b * ENC_ + col] = acc / L;
}

extern "C" void kernel_launch(void* const* d_in, const int* in_sizes, int n_in,
                              void* d_out, int out_size, void* d_ws, size_t ws_size,
                              hipStream_t stream) {
    const float* enc = (const float*)d_in[0];
    const float* W   = (const float*)d_in[2];
    float* out       = (float*)d_out;

    // chunks per batch: fit partials in workspace; keep P mult of 4, R mult of 16
    int P = 128;
    while (P > 4 && (size_t)B_ * P * (ENC_ + 2) * sizeof(float) > ws_size) P >>= 1;
    const int R = S_ / P;

    float* pm = (float*)d_ws;
    float* pl = pm + (size_t)B_ * P;
    float* pc = pl + (size_t)B_ * P;

    dim3 grid1(P / 4, B_);
    attn_partial<<<grid1, TPB, 0, stream>>>(enc, W, pm, pl, pc, R, P);
    dim3 grid2(ENC_ / TPB, B_);
    attn_combine<<<grid2, TPB, 0, stream>>>(pm, pl, pc, out, P);
}

// Round 3
// 54.635 us; speedup vs baseline: 1.5993x; 1.3188x over previous
//
#include <hip/hip_runtime.h>
#include <math.h>

// Attention pooling, B=32, S=4096, ENC=512.
// context[b,e] = sum_s softmax_s(enc[b,s,:]·w_enc) * enc[b,s,e]
// (hidden/w_dec/bias add a per-b constant to energies -> softmax-invariant -> dropped)
//
// Kernel 1: one WAVE per 64-row chunk. Lane l covers cols [4l,4l+4) and
// [256+4l,260+4l) -> each row is read by two fully-contiguous 1KB wave-loads.
// 64-lane butterfly for the energy dot; no LDS, no __syncthreads. 8-row groups,
// ping-pong register double-buffer keeps 16 KB/wave of loads in flight through
// the reduce/softmax chain. Online softmax per group.
//
// Kernel 2: parallel combine. 256 blocks; M/L lane-parallel via butterfly;
// P partials split across 4 waves, LDS cross-wave add.

#define B_ 32
#define S_ 4096
#define ENC_ 512
#define TPB 256
#define G 8

__device__ __forceinline__ float dot4(const float4 a, const float4 b) {
    return a.x * b.x + a.y * b.y + a.z * b.z + a.w * b.w;
}

__global__ __launch_bounds__(TPB) void attn_partial(
    const float* __restrict__ enc,   // [B, S, 512]
    const float* __restrict__ W,     // [1, 1024]; first 512 = w_enc
    float* __restrict__ pm,          // [B*P] partial max
    float* __restrict__ pl,          // [B*P] partial sum
    float* __restrict__ pc,          // [B*P, 512] partial (unnormalized) context
    int R, int P)                    // R = rows per wave-chunk (multiple of 16)
{
    const int b    = blockIdx.y;
    const int wid  = (blockIdx.x << 2) | (threadIdx.x >> 6);  // chunk id in [0,P)
    const int lane = threadIdx.x & 63;
    const int cA0  = lane << 2;            // cols 4l..4l+3
    const int cB0  = 256 + (lane << 2);    // cols 256+4l..259+4l

    const float4 wA = *reinterpret_cast<const float4*>(W + cA0);
    const float4 wB = *reinterpret_cast<const float4*>(W + cB0);

    const float* row = enc + ((size_t)b * S_ + (size_t)wid * R) * ENC_;

    float4 accA = {0.f, 0.f, 0.f, 0.f}, accB = {0.f, 0.f, 0.f, 0.f};
    float m = -INFINITY, l = 0.f;

    float4 dA0[G], dB0[G], dA1[G], dB1[G];

#define LOADG(DA, DB, base_row) { \
    const float* _p = row + (size_t)(base_row) * ENC_; \
    _Pragma("unroll") \
    for (int i = 0; i < G; ++i) { \
        DA[i] = *reinterpret_cast<const float4*>(_p + (size_t)i * ENC_ + cA0); \
        DB[i] = *reinterpret_cast<const float4*>(_p + (size_t)i * ENC_ + cB0); \
    } }

#define PROC(DA, DB) { \
    float e[G]; \
    _Pragma("unroll") \
    for (int i = 0; i < G; ++i) e[i] = dot4(DA[i], wA) + dot4(DB[i], wB); \
    _Pragma("unroll") \
    for (int i = 0; i < G; ++i) { \
        float v = e[i]; \
        v += __shfl_xor(v, 1, 64);  v += __shfl_xor(v, 2, 64); \
        v += __shfl_xor(v, 4, 64);  v += __shfl_xor(v, 8, 64); \
        v += __shfl_xor(v, 16, 64); v += __shfl_xor(v, 32, 64); \
        e[i] = v; \
    } \
    float gm = e[0]; \
    _Pragma("unroll") \
    for (int i = 1; i < G; ++i) gm = fmaxf(gm, e[i]); \
    const float mn = fmaxf(m, gm); \
    const float sc = __expf(m - mn);  /* first group: exp(-inf)=0 */ \
    m = mn; l *= sc; \
    accA.x *= sc; accA.y *= sc; accA.z *= sc; accA.w *= sc; \
    accB.x *= sc; accB.y *= sc; accB.z *= sc; accB.w *= sc; \
    _Pragma("unroll") \
    for (int i = 0; i < G; ++i) { \
        const float pw = __expf(e[i] - mn); l += pw; \
        accA.x += pw * DA[i].x; accA.y += pw * DA[i].y; \
        accA.z += pw * DA[i].z; accA.w += pw * DA[i].w; \
        accB.x += pw * DB[i].x; accB.y += pw * DB[i].y; \
        accB.z += pw * DB[i].z; accB.w += pw * DB[i].w; \
    } }

    LOADG(dA0, dB0, 0);
    const int ng = R / G;             // even (R multiple of 16)
    for (int g = 0; g < ng; g += 2) {
        if (g + 1 < ng) LOADG(dA1, dB1, (g + 1) * G);
        PROC(dA0, dB0);
        if (g + 2 < ng) LOADG(dA0, dB0, (g + 2) * G);
        if (g + 1 < ng) PROC(dA1, dB1);
    }

    const int idx = b * P + wid;
    *reinterpret_cast<float4*>(pc + (size_t)idx * ENC_ + cA0) = accA;
    *reinterpret_cast<float4*>(pc + (size_t)idx * ENC_ + cB0) = accB;
    if (lane == 0) { pm[idx] = m; pl[idx] = l; }

#undef LOADG
#undef PROC
}

// grid (ENC/64, B); 256 threads. Block owns 64 cols; 4 waves split the P
// partials; M and L are computed lane-parallel (P <= 64).
__global__ __launch_bounds__(TPB) void attn_combine(
    const float* __restrict__ pm, const float* __restrict__ pl,
    const float* __restrict__ pc, float* __restrict__ out, int P)
{
    const int b    = blockIdx.y;
    const int lane = threadIdx.x & 63;
    const int wave = threadIdx.x >> 6;
    const int col  = (blockIdx.x << 6) | lane;

    // lane-parallel global max / denom over the P chunk-partials
    const float mv = (lane < P) ? pm[b * P + lane] : -INFINITY;
    float M = mv;
#pragma unroll
    for (int o = 32; o >= 1; o >>= 1) M = fmaxf(M, __shfl_xor(M, o, 64));
    const float sv = (lane < P) ? __expf(mv - M) : 0.f;   // scale for chunk `lane`
    float L = (lane < P) ? pl[b * P + lane] * sv : 0.f;
#pragma unroll
    for (int o = 32; o >= 1; o >>= 1) L += __shfl_xor(L, o, 64);

    const int per = P >> 2;                 // chunks per wave
    float acc = 0.f;
    for (int k = 0; k < per; ++k) {
        const int i = wave * per + k;
        const float s = __shfl(sv, i, 64);
        acc += pc[((size_t)(b * P + i) << 9) | col] * s;
    }

    __shared__ float red[3][64];
    if (wave) red[wave - 1][lane] = acc;
    __syncthreads();
    if (wave == 0) {
        acc += red[0][lane] + red[1][lane] + red[2][lane];
        out[(b << 9) | col] = acc / L;
    }
}

extern "C" void kernel_launch(void* const* d_in, const int* in_sizes, int n_in,
                              void* d_out, int out_size, void* d_ws, size_t ws_size,
                              hipStream_t stream) {
    const float* enc = (const float*)d_in[0];
    const float* W   = (const float*)d_in[2];
    float* out       = (float*)d_out;

    // P chunks per batch (P<=64 so the combine's lane-parallel pass works);
    // shrink if workspace is tiny. R = S/P rows per wave, multiple of 16.
    int P = 64;
    while (P > 4 && (size_t)B_ * P * (ENC_ + 2) * sizeof(float) > ws_size) P >>= 1;
    const int R = S_ / P;

    float* pm = (float*)d_ws;
    float* pl = pm + (size_t)B_ * P;
    float* pc = pl + (size_t)B_ * P;

    dim3 grid1(P / 4, B_);
    attn_partial<<<grid1, TPB, 0, stream>>>(enc, W, pm, pl, pc, R, P);
    dim3 grid2(ENC_ / 64, B_);
    attn_combine<<<grid2, TPB, 0, stream>>>(pm, pl, pc, out, P);
}